// Round 1
// baseline (2189.434 us; speedup 1.0000x reference)
//
#include <hip/hip_runtime.h>
#include <hip/hip_bf16.h>
#include <cfloat>

#define NTOK 4096
#define D_ 1024
#define DICT_ 16384
#define TOPK 8
#define LN_EPS 1e-5f

#define BM 64
#define BN 64
#define KB 16
#define NSUB 16   // dict subtiles per block -> each block covers NSUB*BN = 1024 dict cols
#define NDG (DICT_ / (NSUB * BN))   // 16 dict groups

// ---------------- K1: LayerNorm (two-pass, matches reference) ----------------
__global__ __launch_bounds__(256) void ln_kernel(const float* __restrict__ x,
                                                 const float* __restrict__ gamma,
                                                 const float* __restrict__ beta,
                                                 float* __restrict__ normed) {
    int t = blockIdx.x;
    int tid = threadIdx.x;
    const float4 v = ((const float4*)(x + (size_t)t * D_))[tid];

    float s = v.x + v.y + v.z + v.w;
    #pragma unroll
    for (int off = 32; off > 0; off >>= 1) s += __shfl_down(s, off, 64);
    __shared__ float red[4];
    int wid = tid >> 6, lane = tid & 63;
    if (lane == 0) red[wid] = s;
    __syncthreads();
    float mu = (red[0] + red[1] + red[2] + red[3]) * (1.0f / D_);
    __syncthreads();

    float dx = v.x - mu, dy = v.y - mu, dz = v.z - mu, dw = v.w - mu;
    float ss = dx * dx + dy * dy + dz * dz + dw * dw;
    #pragma unroll
    for (int off = 32; off > 0; off >>= 1) ss += __shfl_down(ss, off, 64);
    if (lane == 0) red[wid] = ss;
    __syncthreads();
    float var = (red[0] + red[1] + red[2] + red[3]) * (1.0f / D_);
    float rs = rsqrtf(var + LN_EPS);

    const float4 g = ((const float4*)gamma)[tid];
    const float4 b = ((const float4*)beta)[tid];
    float4 o;
    o.x = dx * rs * g.x + b.x;
    o.y = dy * rs * g.y + b.y;
    o.z = dz * rs * g.z + b.z;
    o.w = dw * rs * g.w + b.w;
    ((float4*)(normed + (size_t)t * D_))[tid] = o;
}

// ------------- K2: fp32 tiled GEMM + per-dict-slice running top-8 -------------
__global__ __launch_bounds__(256) void logits_topk_kernel(
    const float* __restrict__ normed, const float* __restrict__ Wenc,
    float* __restrict__ cand_val, int* __restrict__ cand_idx) {
    __shared__ float As[KB][68];
    __shared__ float Bs[KB][68];
    __shared__ float Cs[BM][68];

    const int tid = threadIdx.x;
    const int bg = blockIdx.x;   // dict group 0..15
    const int tg = blockIdx.y;   // token group 0..63
    const int row0 = tg * BM;
    const int tx = tid & 15, ty = tid >> 4;
    const int lr = tid >> 2;          // load row 0..63
    const int lk = (tid & 3) * 4;     // load k offset 0,4,8,12

    float tv[TOPK];
    int ti[TOPK];
    #pragma unroll
    for (int j = 0; j < TOPK; j++) { tv[j] = -FLT_MAX; ti[j] = -1; }

    for (int sub = 0; sub < NSUB; sub++) {
        const int col0 = bg * (NSUB * BN) + sub * BN;
        float acc[4][4] = {};
        for (int k0 = 0; k0 < D_; k0 += KB) {
            const float4 a = *(const float4*)(normed + (size_t)(row0 + lr) * D_ + k0 + lk);
            const float4 b = *(const float4*)(Wenc + (size_t)(col0 + lr) * D_ + k0 + lk);
            As[lk + 0][lr] = a.x; As[lk + 1][lr] = a.y; As[lk + 2][lr] = a.z; As[lk + 3][lr] = a.w;
            Bs[lk + 0][lr] = b.x; Bs[lk + 1][lr] = b.y; Bs[lk + 2][lr] = b.z; Bs[lk + 3][lr] = b.w;
            __syncthreads();
            #pragma unroll
            for (int k = 0; k < KB; k++) {
                const float4 av = *(const float4*)&As[k][ty * 4];
                const float4 bv = *(const float4*)&Bs[k][tx * 4];
                const float a4[4] = {av.x, av.y, av.z, av.w};
                const float b4[4] = {bv.x, bv.y, bv.z, bv.w};
                #pragma unroll
                for (int i = 0; i < 4; i++)
                    #pragma unroll
                    for (int j = 0; j < 4; j++)
                        acc[i][j] = fmaf(a4[i], b4[j], acc[i][j]);
            }
            __syncthreads();
        }
        // stash tile to LDS for per-row selection
        #pragma unroll
        for (int i = 0; i < 4; i++) {
            float4 w;
            w.x = acc[i][0]; w.y = acc[i][1]; w.z = acc[i][2]; w.w = acc[i][3];
            *(float4*)&Cs[ty * 4 + i][tx * 4] = w;
        }
        __syncthreads();
        if (tid < BM) {
            #pragma unroll 1
            for (int c = 0; c < BN; c++) {
                const float v = Cs[tid][c];
                if (v > tv[TOPK - 1]) {
                    tv[TOPK - 1] = v;
                    ti[TOPK - 1] = col0 + c;
                    #pragma unroll
                    for (int j = TOPK - 1; j > 0; j--) {
                        if (tv[j] > tv[j - 1]) {
                            float fv = tv[j]; tv[j] = tv[j - 1]; tv[j - 1] = fv;
                            int fi = ti[j]; ti[j] = ti[j - 1]; ti[j - 1] = fi;
                        }
                    }
                }
            }
        }
        __syncthreads();
    }

    if (tid < BM) {
        const int token = row0 + tid;
        const size_t cb = ((size_t)token * NDG + bg) * TOPK;
        #pragma unroll
        for (int j = 0; j < TOPK; j++) {
            cand_val[cb + j] = tv[j];
            cand_idx[cb + j] = ti[j];
        }
    }
}

// ------------- K3: merge 128 candidates/token -> final top-8, scatter ---------
__global__ __launch_bounds__(128) void topk_final_kernel(
    const float* __restrict__ cand_val, const int* __restrict__ cand_idx,
    float* __restrict__ sel_val, int* __restrict__ sel_idx,
    float* __restrict__ sparse) {
    const int token = blockIdx.x;
    const int tid = threadIdx.x;
    __shared__ float sv[128];
    __shared__ int si[128];
    __shared__ float rv[64];
    __shared__ int rp[64];
    __shared__ float wv[TOPK];
    __shared__ int wi[TOPK];

    sv[tid] = cand_val[(size_t)token * 128 + tid];
    si[tid] = cand_idx[(size_t)token * 128 + tid];
    __syncthreads();

    for (int pass = 0; pass < TOPK; pass++) {
        if (tid < 64) {
            float v = sv[tid]; int p = tid;
            if (sv[tid + 64] > v) { v = sv[tid + 64]; p = tid + 64; }
            rv[tid] = v; rp[tid] = p;
        }
        __syncthreads();
        for (int strd = 32; strd > 0; strd >>= 1) {
            if (tid < strd) {
                if (rv[tid + strd] > rv[tid]) { rv[tid] = rv[tid + strd]; rp[tid] = rp[tid + strd]; }
            }
            __syncthreads();
        }
        if (tid == 0) {
            const int p = rp[0];
            wv[pass] = sv[p];
            wi[pass] = si[p];
            sv[p] = -FLT_MAX;  // disable winner
        }
        __syncthreads();
    }

    if (tid < TOPK) {
        sel_val[(size_t)token * TOPK + tid] = wv[tid];
        sel_idx[(size_t)token * TOPK + tid] = wi[tid];
        sparse[(size_t)token * DICT_ + wi[tid]] = wv[tid];
    }
}

// ------------- K4: reconstruction = sum of 8 scaled W_dict rows ---------------
__global__ __launch_bounds__(256) void recon_kernel(
    const float* __restrict__ sel_val, const int* __restrict__ sel_idx,
    const float* __restrict__ Wdict, float* __restrict__ recon) {
    const int token = blockIdx.x;
    const int tid = threadIdx.x;
    __shared__ float v8[TOPK];
    __shared__ int i8[TOPK];
    if (tid < TOPK) {
        v8[tid] = sel_val[(size_t)token * TOPK + tid];
        i8[tid] = sel_idx[(size_t)token * TOPK + tid];
    }
    __syncthreads();
    float4 acc = {0.f, 0.f, 0.f, 0.f};
    #pragma unroll
    for (int j = 0; j < TOPK; j++) {
        const float4 w = ((const float4*)(Wdict + (size_t)i8[j] * D_))[tid];
        const float c = v8[j];
        acc.x = fmaf(c, w.x, acc.x);
        acc.y = fmaf(c, w.y, acc.y);
        acc.z = fmaf(c, w.z, acc.z);
        acc.w = fmaf(c, w.w, acc.w);
    }
    ((float4*)(recon + (size_t)token * D_))[tid] = acc;
}

extern "C" void kernel_launch(void* const* d_in, const int* in_sizes, int n_in,
                              void* d_out, int out_size, void* d_ws, size_t ws_size,
                              hipStream_t stream) {
    const float* x = (const float*)d_in[0];
    const float* gamma = (const float*)d_in[1];
    const float* beta = (const float*)d_in[2];
    const float* Wenc = (const float*)d_in[3];
    const float* Wdict = (const float*)d_in[4];

    float* recon = (float*)d_out;
    float* sparse = (float*)d_out + (size_t)NTOK * D_;

    float* ws = (float*)d_ws;
    float* normed = ws;                                        // 4096*1024 f32
    float* cand_val = normed + (size_t)NTOK * D_;              // 4096*16*8 f32
    int* cand_idx = (int*)(cand_val + (size_t)NTOK * NDG * TOPK);
    float* sel_val = (float*)(cand_idx + (size_t)NTOK * NDG * TOPK);
    int* sel_idx = (int*)(sel_val + (size_t)NTOK * TOPK);

    // zero the sparse-coefficient output region (scatter fills top-8 later)
    hipMemsetAsync(sparse, 0, (size_t)NTOK * DICT_ * sizeof(float), stream);

    ln_kernel<<<NTOK, 256, 0, stream>>>(x, gamma, beta, normed);

    dim3 g2(NDG, NTOK / BM);
    logits_topk_kernel<<<g2, 256, 0, stream>>>(normed, Wenc, cand_val, cand_idx);

    topk_final_kernel<<<NTOK, 128, 0, stream>>>(cand_val, cand_idx, sel_val, sel_idx, sparse);

    recon_kernel<<<NTOK, 256, 0, stream>>>(sel_val, sel_idx, Wdict, recon);
}

// Round 2
// 365.201 us; speedup vs baseline: 5.9951x; 5.9951x over previous
//
#include <hip/hip_runtime.h>
#include <hip/hip_bf16.h>
#include <cfloat>

#define NTOK 4096
#define D_ 1024
#define DICT_ 16384
#define TOPK 8
#define NCAND 16
#define LN_EPS 1e-5f

typedef __attribute__((ext_vector_type(8))) short bf16x8;
typedef __attribute__((ext_vector_type(4))) float f32x4;
typedef __attribute__((ext_vector_type(8))) unsigned short us8;
typedef __attribute__((ext_vector_type(4))) unsigned short us4;

__device__ __forceinline__ unsigned short f2bf(float f) {
    unsigned int u = __float_as_uint(f);
    u += 0x7fffu + ((u >> 16) & 1u);   // RNE
    return (unsigned short)(u >> 16);
}
__device__ __forceinline__ float bf2f(unsigned short u) {
    return __uint_as_float(((unsigned int)u) << 16);
}

__device__ __forceinline__ void gl2lds16(const void* gsrc, void* ldsdst) {
    __builtin_amdgcn_global_load_lds(
        (const __attribute__((address_space(1))) unsigned int*)gsrc,
        (__attribute__((address_space(3))) unsigned int*)ldsdst, 16, 0, 0);
}

// ---------------- K1: LayerNorm -> bf16 normed ----------------
__global__ __launch_bounds__(256) void ln_kernel(const float* __restrict__ x,
                                                 const float* __restrict__ gamma,
                                                 const float* __restrict__ beta,
                                                 unsigned short* __restrict__ nb) {
    int t = blockIdx.x;
    int tid = threadIdx.x;
    const float4 v = ((const float4*)(x + (size_t)t * D_))[tid];

    float s = v.x + v.y + v.z + v.w;
    #pragma unroll
    for (int off = 32; off > 0; off >>= 1) s += __shfl_down(s, off, 64);
    __shared__ float red[4];
    int wid = tid >> 6, lane = tid & 63;
    if (lane == 0) red[wid] = s;
    __syncthreads();
    float mu = (red[0] + red[1] + red[2] + red[3]) * (1.0f / D_);
    __syncthreads();

    float dx = v.x - mu, dy = v.y - mu, dz = v.z - mu, dw = v.w - mu;
    float ss = dx * dx + dy * dy + dz * dz + dw * dw;
    #pragma unroll
    for (int off = 32; off > 0; off >>= 1) ss += __shfl_down(ss, off, 64);
    if (lane == 0) red[wid] = ss;
    __syncthreads();
    float var = (red[0] + red[1] + red[2] + red[3]) * (1.0f / D_);
    float rs = rsqrtf(var + LN_EPS);

    const float4 g = ((const float4*)gamma)[tid];
    const float4 b = ((const float4*)beta)[tid];
    us4 o;
    o.x = f2bf(dx * rs * g.x + b.x);
    o.y = f2bf(dy * rs * g.y + b.y);
    o.z = f2bf(dz * rs * g.z + b.z);
    o.w = f2bf(dw * rs * g.w + b.w);
    ((us4*)(nb + (size_t)t * D_))[tid] = o;
}

// ---------------- K1b: W_enc fp32 -> bf16 ----------------
__global__ __launch_bounds__(256) void cvt_kernel(const float* __restrict__ W,
                                                  unsigned short* __restrict__ Wb) {
    const int tid = threadIdx.x;
    const size_t base = (size_t)blockIdx.x * 1024;
    #pragma unroll
    for (int j = 0; j < 4; j++) {
        size_t i = base + j * 256 + tid;
        float4 f = ((const float4*)W)[i];
        us4 o;
        o.x = f2bf(f.x); o.y = f2bf(f.y); o.z = f2bf(f.z); o.w = f2bf(f.w);
        ((us4*)Wb)[i] = o;
    }
}

// ---------------- K2: bf16 MFMA GEMM -> bf16 logits ----------------
// 128x128 tile, BK=32, 256 threads (4 waves, 2x2), each wave 64x64 (4x4 frags)
__global__ __launch_bounds__(256) void gemm_kernel(const unsigned short* __restrict__ A,
                                                   const unsigned short* __restrict__ B,
                                                   unsigned short* __restrict__ L) {
    __shared__ unsigned short As[128 * 32];
    __shared__ unsigned short Bs[128 * 32];
    const int tid = threadIdx.x;
    const int lane = tid & 63;
    const int col0 = blockIdx.x * 128;   // dict col
    const int row0 = blockIdx.y * 128;   // token row
    const int w = tid >> 6;
    const int wr = (w >> 1) * 64, wc = (w & 1) * 64;
    const int wbase = (tid & ~63) * 8;   // shorts: wave's 64-lane LDS segment (64*8 shorts per chunk-group)

    f32x4 acc[4][4] = {};

    for (int k0 = 0; k0 < D_; k0 += 32) {
        // stage A,B: 512 chunks of 16B each (8 shorts). slot s -> row=s>>2, swizzled k-group
        #pragma unroll
        for (int i = 0; i < 2; i++) {
            const int s = i * 256 + tid;
            const int r = s >> 2;
            const int ko = ((s & 3) ^ (r & 3)) * 8;
            gl2lds16(A + (size_t)(row0 + r) * D_ + k0 + ko, &As[i * 2048 + wbase]);
        }
        #pragma unroll
        for (int i = 0; i < 2; i++) {
            const int s = i * 256 + tid;
            const int r = s >> 2;
            const int ko = ((s & 3) ^ (r & 3)) * 8;
            gl2lds16(B + (size_t)(col0 + r) * D_ + k0 + ko, &Bs[i * 2048 + wbase]);
        }
        __syncthreads();

        bf16x8 af[4], bfr[4];
        const int kg = lane >> 4;
        #pragma unroll
        for (int m = 0; m < 4; m++) {
            const int row = wr + m * 16 + (lane & 15);
            af[m] = *(const bf16x8*)&As[row * 32 + (kg ^ (row & 3)) * 8];
        }
        #pragma unroll
        for (int n = 0; n < 4; n++) {
            const int row = wc + n * 16 + (lane & 15);
            bfr[n] = *(const bf16x8*)&Bs[row * 32 + (kg ^ (row & 3)) * 8];
        }
        #pragma unroll
        for (int m = 0; m < 4; m++)
            #pragma unroll
            for (int n = 0; n < 4; n++)
                acc[m][n] = __builtin_amdgcn_mfma_f32_16x16x32_bf16(af[m], bfr[n], acc[m][n], 0, 0, 0);
        __syncthreads();
    }

    // epilogue: C/D layout col=lane&15, row=(lane>>4)*4+reg
    #pragma unroll
    for (int m = 0; m < 4; m++) {
        #pragma unroll
        for (int n = 0; n < 4; n++) {
            const int col = col0 + wc + n * 16 + (lane & 15);
            #pragma unroll
            for (int r = 0; r < 4; r++) {
                const int row = row0 + wr + m * 16 + (lane >> 4) * 4 + r;
                L[(size_t)row * DICT_ + col] = f2bf(acc[m][n][r]);
            }
        }
    }
}

// ---------------- K3: per-token top-16 candidates from bf16 logits ----------------
__global__ __launch_bounds__(256) void cand_kernel(const unsigned short* __restrict__ L,
                                                   int* __restrict__ cand) {
    const int token = blockIdx.x;
    const int tid = threadIdx.x;
    const unsigned short* row = L + (size_t)token * DICT_;

    float v[4];
    int id[4];
    #pragma unroll
    for (int j = 0; j < 4; j++) { v[j] = -FLT_MAX; id[j] = -1; }

    for (int j = 0; j < 8; j++) {
        const int fi = j * 256 + tid;            // 16B group index (2048 per row)
        const us8 u = *(const us8*)&row[fi * 8];
        #pragma unroll
        for (int e = 0; e < 8; e++) {
            const float f = bf2f(u[e]);
            if (f > v[3]) {
                v[3] = f; id[3] = fi * 8 + e;
                #pragma unroll
                for (int q = 3; q > 0; q--) {
                    if (v[q] > v[q - 1]) {
                        float tv = v[q]; v[q] = v[q - 1]; v[q - 1] = tv;
                        int ti = id[q]; id[q] = id[q - 1]; id[q - 1] = ti;
                    }
                }
            }
        }
    }

    __shared__ float hv[256];
    __shared__ int hi[256];
    __shared__ int hp[256];
    __shared__ int wt;
    hv[tid] = v[0];
    hi[tid] = id[0];
    hp[tid] = 0;

    for (int round = 0; round < NCAND; round++) {
        __syncthreads();
        if (tid < 64) {
            float bv = hv[tid]; int bt = tid;
            #pragma unroll
            for (int q = 1; q < 4; q++) {
                const int t2 = tid + q * 64;
                const float v2 = hv[t2];
                if (v2 > bv || (v2 == bv && t2 < bt)) { bv = v2; bt = t2; }
            }
            #pragma unroll
            for (int off = 32; off > 0; off >>= 1) {
                const float ov = __shfl_down(bv, off, 64);
                const int ot = __shfl_down(bt, off, 64);
                if (ov > bv || (ov == bv && ot < bt)) { bv = ov; bt = ot; }
            }
            if (tid == 0) wt = bt;
        }
        __syncthreads();
        if (tid == wt) {
            cand[(size_t)token * NCAND + round] = hi[tid];
            const int p = hp[tid] + 1;
            hp[tid] = p;
            if (p < 4) { hv[tid] = v[p]; hi[tid] = id[p]; }
            else { hv[tid] = -FLT_MAX; hi[tid] = -1; }
        }
    }
}

// ---------------- K4: exact fp32 refine of 16 candidates -> top-8, scatter ----------------
__global__ __launch_bounds__(256) void refine_kernel(const float* __restrict__ x,
                                                     const float* __restrict__ gamma,
                                                     const float* __restrict__ beta,
                                                     const float* __restrict__ Wenc,
                                                     const int* __restrict__ cand,
                                                     float* __restrict__ sparse,
                                                     float* __restrict__ sel_val,
                                                     int* __restrict__ sel_idx) {
    const int token = blockIdx.x;
    const int tid = threadIdx.x;
    const int lane = tid & 63;
    const int w = tid >> 6;

    __shared__ float red[4];
    __shared__ float ln[D_];

    const float4 v = ((const float4*)(x + (size_t)token * D_))[tid];
    float s = v.x + v.y + v.z + v.w;
    #pragma unroll
    for (int off = 32; off > 0; off >>= 1) s += __shfl_down(s, off, 64);
    if (lane == 0) red[w] = s;
    __syncthreads();
    float mu = (red[0] + red[1] + red[2] + red[3]) * (1.0f / D_);
    __syncthreads();
    float dx = v.x - mu, dy = v.y - mu, dz = v.z - mu, dw = v.w - mu;
    float ss = dx * dx + dy * dy + dz * dz + dw * dw;
    #pragma unroll
    for (int off = 32; off > 0; off >>= 1) ss += __shfl_down(ss, off, 64);
    if (lane == 0) red[w] = ss;
    __syncthreads();
    float var = (red[0] + red[1] + red[2] + red[3]) * (1.0f / D_);
    float rs = rsqrtf(var + LN_EPS);
    const float4 g = ((const float4*)gamma)[tid];
    const float4 b = ((const float4*)beta)[tid];
    float4 o;
    o.x = dx * rs * g.x + b.x;
    o.y = dy * rs * g.y + b.y;
    o.z = dz * rs * g.z + b.z;
    o.w = dw * rs * g.w + b.w;
    ((float4*)ln)[tid] = o;
    __syncthreads();

    __shared__ float dv[NCAND];
    __shared__ int di_s[NCAND];
    for (int c = w; c < NCAND; c += 4) {
        const int di = cand[(size_t)token * NCAND + c];
        const float4* wr = (const float4*)(Wenc + (size_t)di * D_);
        float acc = 0.f;
        #pragma unroll
        for (int j = 0; j < 4; j++) {
            const float4 q = wr[j * 64 + lane];
            const float4 p = ((const float4*)ln)[j * 64 + lane];
            acc += q.x * p.x + q.y * p.y + q.z * p.z + q.w * p.w;
        }
        #pragma unroll
        for (int off = 32; off > 0; off >>= 1) acc += __shfl_down(acc, off, 64);
        if (lane == 0) { dv[c] = acc; di_s[c] = di; }
    }
    __syncthreads();

    __shared__ float wv[TOPK];
    __shared__ int wi[TOPK];
    if (tid == 0) {
        unsigned int used = 0;
        for (int p = 0; p < TOPK; p++) {
            float bv = -FLT_MAX; int bc = -1;
            for (int c = 0; c < NCAND; c++) {
                if (used & (1u << c)) continue;
                const float cv = dv[c];
                if (cv > bv || (cv == bv && di_s[c] < ((bc >= 0) ? di_s[bc] : 0x7fffffff))) { bv = cv; bc = c; }
            }
            used |= 1u << bc;
            wv[p] = dv[bc]; wi[p] = di_s[bc];
        }
    }
    __syncthreads();
    if (tid < TOPK) {
        sel_val[(size_t)token * TOPK + tid] = wv[tid];
        sel_idx[(size_t)token * TOPK + tid] = wi[tid];
        sparse[(size_t)token * DICT_ + wi[tid]] = wv[tid];
    }
}

// ---------------- K5: reconstruction ----------------
__global__ __launch_bounds__(256) void recon_kernel(const float* __restrict__ sel_val,
                                                    const int* __restrict__ sel_idx,
                                                    const float* __restrict__ Wdict,
                                                    float* __restrict__ recon) {
    const int token = blockIdx.x;
    const int tid = threadIdx.x;
    __shared__ float v8[TOPK];
    __shared__ int i8[TOPK];
    if (tid < TOPK) {
        v8[tid] = sel_val[(size_t)token * TOPK + tid];
        i8[tid] = sel_idx[(size_t)token * TOPK + tid];
    }
    __syncthreads();
    float4 acc = {0.f, 0.f, 0.f, 0.f};
    #pragma unroll
    for (int j = 0; j < TOPK; j++) {
        const float4 wv = ((const float4*)(Wdict + (size_t)i8[j] * D_))[tid];
        const float c = v8[j];
        acc.x = fmaf(c, wv.x, acc.x);
        acc.y = fmaf(c, wv.y, acc.y);
        acc.z = fmaf(c, wv.z, acc.z);
        acc.w = fmaf(c, wv.w, acc.w);
    }
    ((float4*)(recon + (size_t)token * D_))[tid] = acc;
}

extern "C" void kernel_launch(void* const* d_in, const int* in_sizes, int n_in,
                              void* d_out, int out_size, void* d_ws, size_t ws_size,
                              hipStream_t stream) {
    const float* x = (const float*)d_in[0];
    const float* gamma = (const float*)d_in[1];
    const float* beta = (const float*)d_in[2];
    const float* Wenc = (const float*)d_in[3];
    const float* Wdict = (const float*)d_in[4];

    float* recon = (float*)d_out;
    float* sparse = (float*)d_out + (size_t)NTOK * D_;

    // scratch carved out of the (later re-zeroed) sparse output region:
    unsigned short* Lg = (unsigned short*)sparse;                 // bf16 logits, 134 MB
    unsigned short* We = Lg + (size_t)NTOK * DICT_;               // bf16 W_enc, 33.5 MB
    unsigned short* Nb = We + (size_t)DICT_ * D_;                 // bf16 normed, 8 MB

    int* cand = (int*)d_ws;                                       // 4096*16 int
    float* sel_val = (float*)(cand + (size_t)NTOK * NCAND);       // 4096*8 f32
    int* sel_idx = (int*)(sel_val + (size_t)NTOK * TOPK);         // 4096*8 int

    ln_kernel<<<NTOK, 256, 0, stream>>>(x, gamma, beta, Nb);
    cvt_kernel<<<DICT_ * D_ / 4096, 256, 0, stream>>>(Wenc, We);

    dim3 gg(DICT_ / 128, NTOK / 128);
    gemm_kernel<<<gg, 256, 0, stream>>>(Nb, We, Lg);

    cand_kernel<<<NTOK, 256, 0, stream>>>(Lg, cand);

    hipMemsetAsync(sparse, 0, (size_t)NTOK * DICT_ * sizeof(float), stream);

    refine_kernel<<<NTOK, 256, 0, stream>>>(x, gamma, beta, Wenc, cand,
                                            sparse, sel_val, sel_idx);

    recon_kernel<<<NTOK, 256, 0, stream>>>(sel_val, sel_idx, Wdict, recon);
}

// Round 3
// 317.173 us; speedup vs baseline: 6.9030x; 1.1514x over previous
//
#include <hip/hip_runtime.h>
#include <hip/hip_bf16.h>
#include <cfloat>

#define NTOK 4096
#define D_ 1024
#define DICT_ 16384
#define TOPK 8
#define NCAND 12
#define LN_EPS 1e-5f

typedef __attribute__((ext_vector_type(8))) short bf16x8;
typedef __attribute__((ext_vector_type(4))) float f32x4;
typedef __attribute__((ext_vector_type(8))) unsigned short us8;
typedef __attribute__((ext_vector_type(4))) unsigned short us4;

__device__ __forceinline__ unsigned short f2bf(float f) {
    unsigned int u = __float_as_uint(f);
    u += 0x7fffu + ((u >> 16) & 1u);   // RNE
    return (unsigned short)(u >> 16);
}
__device__ __forceinline__ float bf2f(unsigned short u) {
    return __uint_as_float(((unsigned int)u) << 16);
}

__device__ __forceinline__ void gl2lds16(const void* gsrc, void* ldsdst) {
    __builtin_amdgcn_global_load_lds(
        (const __attribute__((address_space(1))) unsigned int*)gsrc,
        (__attribute__((address_space(3))) unsigned int*)ldsdst, 16, 0, 0);
}

// ---------------- K1: LayerNorm -> bf16 normed ----------------
__global__ __launch_bounds__(256) void ln_kernel(const float* __restrict__ x,
                                                 const float* __restrict__ gamma,
                                                 const float* __restrict__ beta,
                                                 unsigned short* __restrict__ nb) {
    int t = blockIdx.x;
    int tid = threadIdx.x;
    const float4 v = ((const float4*)(x + (size_t)t * D_))[tid];

    float s = v.x + v.y + v.z + v.w;
    #pragma unroll
    for (int off = 32; off > 0; off >>= 1) s += __shfl_down(s, off, 64);
    __shared__ float red[4];
    int wid = tid >> 6, lane = tid & 63;
    if (lane == 0) red[wid] = s;
    __syncthreads();
    float mu = (red[0] + red[1] + red[2] + red[3]) * (1.0f / D_);
    __syncthreads();

    float dx = v.x - mu, dy = v.y - mu, dz = v.z - mu, dw = v.w - mu;
    float ss = dx * dx + dy * dy + dz * dz + dw * dw;
    #pragma unroll
    for (int off = 32; off > 0; off >>= 1) ss += __shfl_down(ss, off, 64);
    if (lane == 0) red[wid] = ss;
    __syncthreads();
    float var = (red[0] + red[1] + red[2] + red[3]) * (1.0f / D_);
    float rs = rsqrtf(var + LN_EPS);

    const float4 g = ((const float4*)gamma)[tid];
    const float4 b = ((const float4*)beta)[tid];
    us4 o;
    o.x = f2bf(dx * rs * g.x + b.x);
    o.y = f2bf(dy * rs * g.y + b.y);
    o.z = f2bf(dz * rs * g.z + b.z);
    o.w = f2bf(dw * rs * g.w + b.w);
    ((us4*)(nb + (size_t)t * D_))[tid] = o;
}

// ---------------- K1b: W_enc fp32 -> bf16 ----------------
__global__ __launch_bounds__(256) void cvt_kernel(const float* __restrict__ W,
                                                  unsigned short* __restrict__ Wb) {
    const int tid = threadIdx.x;
    const size_t base = (size_t)blockIdx.x * 1024;
    #pragma unroll
    for (int j = 0; j < 4; j++) {
        size_t i = base + j * 256 + tid;
        float4 f = ((const float4*)W)[i];
        us4 o;
        o.x = f2bf(f.x); o.y = f2bf(f.y); o.z = f2bf(f.z); o.w = f2bf(f.w);
        ((us4*)Wb)[i] = o;
    }
}

// ---------------- K2: 256x256 bf16 MFMA GEMM, counted-vmcnt phase schedule ----------------
// 512 threads = 8 waves (2M x 4N). Wave tile 128x64 (8x4 16x16 frags). BK=64.
// LDS: 2 buffers x (A 256x64 + B 256x64) bf16 = 128 KiB, 3-bit XOR swizzle.
__global__ __launch_bounds__(512, 1) void gemm_kernel(const unsigned short* __restrict__ A,
                                                      const unsigned short* __restrict__ B,
                                                      unsigned short* __restrict__ L) {
    __shared__ unsigned short lds[2][2][256][64];
    const int tid = threadIdx.x;
    const int lane = tid & 63;
    const int w = tid >> 6;
    const int wm = w >> 2, wn = w & 3;
    const int col0 = blockIdx.x * 256;   // dict cols
    const int row0 = blockIdx.y * 256;   // token rows

    f32x4 acc[8][4] = {};

    // stage one 128-row half (16KB = 1024 chunks of 16B): 2 chunks/thread.
    // chunk c -> row r=c>>3, slot sl=c&7 holds k-group g = sl ^ (r&7)  (pre-swizzled source)
    auto stage = [&](int b, int mat, const unsigned short* __restrict__ G,
                     int rbase, int k0, int h) {
        unsigned short* plane = &lds[b][mat][0][0];
        #pragma unroll
        for (int i = 0; i < 2; i++) {
            const int cb = h * 1024 + i * 512 + w * 64;   // wave-uniform chunk base
            const int c = cb + lane;
            const int r = c >> 3, sl = c & 7, g = sl ^ (r & 7);
            gl2lds16(G + (size_t)(rbase + r) * 1024 + k0 + g * 8, plane + (size_t)cb * 8);
        }
    };

    // prologue: stage tile 0 into buf 0 (8 loads/thread outstanding)
    stage(0, 0, A, row0, 0, 0);
    stage(0, 0, A, row0, 0, 1);
    stage(0, 1, B, col0, 0, 0);
    stage(0, 1, B, col0, 0, 1);

    const int arow = wm * 128 + (lane & 15);
    const int brow = wn * 64 + (lane & 15);
    const int kg = lane >> 4;   // k-group within 32-wide k-step

    for (int t = 0; t < 16; t++) {
        const int cur = t & 1, nxt = cur ^ 1;
        const int kn = ((t + 1) & 15) * 64;   // wrap-around keeps loop uniform

        // ---- phase 0: issue next A halves; wait tile t (leave 4 in flight); kk0, n={0,1}
        stage(nxt, 0, A, row0, kn, 0);
        stage(nxt, 0, A, row0, kn, 1);
        asm volatile("s_waitcnt vmcnt(4)" ::: "memory");
        __builtin_amdgcn_s_barrier();
        __builtin_amdgcn_sched_barrier(0);
        asm volatile("" ::: "memory");

        bf16x8 af[8];
        #pragma unroll
        for (int m = 0; m < 8; m++) {
            const int r = arow + m * 16;
            af[m] = *(const bf16x8*)&lds[cur][0][r][(kg ^ (r & 7)) * 8];
        }
        bf16x8 b0, b1;
        { const int r = brow;      b0 = *(const bf16x8*)&lds[cur][1][r][(kg ^ (r & 7)) * 8]; }
        { const int r = brow + 16; b1 = *(const bf16x8*)&lds[cur][1][r][(kg ^ (r & 7)) * 8]; }
        __builtin_amdgcn_s_setprio(1);
        #pragma unroll
        for (int m = 0; m < 8; m++) {
            acc[m][0] = __builtin_amdgcn_mfma_f32_16x16x32_bf16(af[m], b0, acc[m][0], 0, 0, 0);
            acc[m][1] = __builtin_amdgcn_mfma_f32_16x16x32_bf16(af[m], b1, acc[m][1], 0, 0, 0);
        }
        __builtin_amdgcn_s_setprio(0);

        // ---- phase 1: issue next B halves; kk0, n={2,3}
        stage(nxt, 1, B, col0, kn, 0);
        stage(nxt, 1, B, col0, kn, 1);
        { const int r = brow + 32; b0 = *(const bf16x8*)&lds[cur][1][r][(kg ^ (r & 7)) * 8]; }
        { const int r = brow + 48; b1 = *(const bf16x8*)&lds[cur][1][r][(kg ^ (r & 7)) * 8]; }
        __builtin_amdgcn_s_setprio(1);
        #pragma unroll
        for (int m = 0; m < 8; m++) {
            acc[m][2] = __builtin_amdgcn_mfma_f32_16x16x32_bf16(af[m], b0, acc[m][2], 0, 0, 0);
            acc[m][3] = __builtin_amdgcn_mfma_f32_16x16x32_bf16(af[m], b1, acc[m][3], 0, 0, 0);
        }
        __builtin_amdgcn_s_setprio(0);

        // ---- phase 2: kk1, n={0,1}
        #pragma unroll
        for (int m = 0; m < 8; m++) {
            const int r = arow + m * 16;
            af[m] = *(const bf16x8*)&lds[cur][0][r][((4 + kg) ^ (r & 7)) * 8];
        }
        { const int r = brow;      b0 = *(const bf16x8*)&lds[cur][1][r][((4 + kg) ^ (r & 7)) * 8]; }
        { const int r = brow + 16; b1 = *(const bf16x8*)&lds[cur][1][r][((4 + kg) ^ (r & 7)) * 8]; }
        __builtin_amdgcn_s_setprio(1);
        #pragma unroll
        for (int m = 0; m < 8; m++) {
            acc[m][0] = __builtin_amdgcn_mfma_f32_16x16x32_bf16(af[m], b0, acc[m][0], 0, 0, 0);
            acc[m][1] = __builtin_amdgcn_mfma_f32_16x16x32_bf16(af[m], b1, acc[m][1], 0, 0, 0);
        }
        __builtin_amdgcn_s_setprio(0);

        // ---- phase 3: kk1, n={2,3}
        { const int r = brow + 32; b0 = *(const bf16x8*)&lds[cur][1][r][((4 + kg) ^ (r & 7)) * 8]; }
        { const int r = brow + 48; b1 = *(const bf16x8*)&lds[cur][1][r][((4 + kg) ^ (r & 7)) * 8]; }
        __builtin_amdgcn_s_setprio(1);
        #pragma unroll
        for (int m = 0; m < 8; m++) {
            acc[m][2] = __builtin_amdgcn_mfma_f32_16x16x32_bf16(af[m], b0, acc[m][2], 0, 0, 0);
            acc[m][3] = __builtin_amdgcn_mfma_f32_16x16x32_bf16(af[m], b1, acc[m][3], 0, 0, 0);
        }
        __builtin_amdgcn_s_setprio(0);

        // end of iter: all reads of buf[cur] done; next iter may overwrite buf[cur]
        __builtin_amdgcn_s_barrier();
        __builtin_amdgcn_sched_barrier(0);
        asm volatile("" ::: "memory");
    }

    // epilogue: C/D layout col=lane&15, row=(lane>>4)*4+reg
    #pragma unroll
    for (int m = 0; m < 8; m++) {
        const int rb = row0 + wm * 128 + m * 16 + (lane >> 4) * 4;
        #pragma unroll
        for (int n = 0; n < 4; n++) {
            const int col = col0 + wn * 64 + n * 16 + (lane & 15);
            #pragma unroll
            for (int r = 0; r < 4; r++)
                L[(size_t)(rb + r) * DICT_ + col] = f2bf(acc[m][n][r]);
        }
    }
}

// ---------------- K3: per-token top-12 candidates from bf16 logits ----------------
__global__ __launch_bounds__(256) void cand_kernel(const unsigned short* __restrict__ L,
                                                   int* __restrict__ cand) {
    const int token = blockIdx.x;
    const int tid = threadIdx.x;
    const unsigned short* row = L + (size_t)token * DICT_;

    float v[5];
    int id[5];
    #pragma unroll
    for (int j = 0; j < 5; j++) { v[j] = -FLT_MAX; id[j] = -1; }

    for (int j = 0; j < 8; j++) {
        const int fi = j * 256 + tid;            // 16B group index (2048 per row)
        const us8 u = *(const us8*)&row[fi * 8];
        #pragma unroll
        for (int e = 0; e < 8; e++) {
            const float f = bf2f(u[e]);
            if (f > v[4]) {
                v[4] = f; id[4] = fi * 8 + e;
                #pragma unroll
                for (int q = 4; q > 0; q--) {
                    if (v[q] > v[q - 1]) {
                        float tv = v[q]; v[q] = v[q - 1]; v[q - 1] = tv;
                        int ti = id[q]; id[q] = id[q - 1]; id[q - 1] = ti;
                    }
                }
            }
        }
    }

    __shared__ float hv[256];
    __shared__ int hi[256];
    __shared__ int hp[256];
    __shared__ int wt;
    hv[tid] = v[0];
    hi[tid] = id[0];
    hp[tid] = 0;

    for (int round = 0; round < NCAND; round++) {
        __syncthreads();
        if (tid < 64) {
            float bv = hv[tid]; int bt = tid;
            #pragma unroll
            for (int q = 1; q < 4; q++) {
                const int t2 = tid + q * 64;
                const float v2 = hv[t2];
                if (v2 > bv || (v2 == bv && t2 < bt)) { bv = v2; bt = t2; }
            }
            #pragma unroll
            for (int off = 32; off > 0; off >>= 1) {
                const float ov = __shfl_down(bv, off, 64);
                const int ot = __shfl_down(bt, off, 64);
                if (ov > bv || (ov == bv && ot < bt)) { bv = ov; bt = ot; }
            }
            if (tid == 0) wt = bt;
        }
        __syncthreads();
        if (tid == wt) {
            cand[(size_t)token * NCAND + round] = hi[tid];
            const int p = hp[tid] + 1;
            hp[tid] = p;
            if (p < 5) { hv[tid] = v[p]; hi[tid] = id[p]; }
            else { hv[tid] = -FLT_MAX; hi[tid] = -1; }
        }
    }
}

// ---------------- K4: exact fp32 refine of 12 candidates -> top-8, scatter ----------------
__global__ __launch_bounds__(256) void refine_kernel(const float* __restrict__ x,
                                                     const float* __restrict__ gamma,
                                                     const float* __restrict__ beta,
                                                     const float* __restrict__ Wenc,
                                                     const int* __restrict__ cand,
                                                     float* __restrict__ sparse,
                                                     float* __restrict__ sel_val,
                                                     int* __restrict__ sel_idx) {
    const int token = blockIdx.x;
    const int tid = threadIdx.x;
    const int lane = tid & 63;
    const int w = tid >> 6;

    __shared__ float red[4];
    __shared__ float ln[D_];

    const float4 v = ((const float4*)(x + (size_t)token * D_))[tid];
    float s = v.x + v.y + v.z + v.w;
    #pragma unroll
    for (int off = 32; off > 0; off >>= 1) s += __shfl_down(s, off, 64);
    if (lane == 0) red[w] = s;
    __syncthreads();
    float mu = (red[0] + red[1] + red[2] + red[3]) * (1.0f / D_);
    __syncthreads();
    float dx = v.x - mu, dy = v.y - mu, dz = v.z - mu, dw = v.w - mu;
    float ss = dx * dx + dy * dy + dz * dz + dw * dw;
    #pragma unroll
    for (int off = 32; off > 0; off >>= 1) ss += __shfl_down(ss, off, 64);
    if (lane == 0) red[w] = ss;
    __syncthreads();
    float var = (red[0] + red[1] + red[2] + red[3]) * (1.0f / D_);
    float rs = rsqrtf(var + LN_EPS);
    const float4 g = ((const float4*)gamma)[tid];
    const float4 b = ((const float4*)beta)[tid];
    float4 o;
    o.x = dx * rs * g.x + b.x;
    o.y = dy * rs * g.y + b.y;
    o.z = dz * rs * g.z + b.z;
    o.w = dw * rs * g.w + b.w;
    ((float4*)ln)[tid] = o;
    __syncthreads();

    __shared__ float dv[NCAND];
    __shared__ int di_s[NCAND];
    for (int c = w; c < NCAND; c += 4) {
        const int di = cand[(size_t)token * NCAND + c];
        const float4* wr = (const float4*)(Wenc + (size_t)di * D_);
        float acc = 0.f;
        #pragma unroll
        for (int j = 0; j < 4; j++) {
            const float4 q = wr[j * 64 + lane];
            const float4 p = ((const float4*)ln)[j * 64 + lane];
            acc += q.x * p.x + q.y * p.y + q.z * p.z + q.w * p.w;
        }
        #pragma unroll
        for (int off = 32; off > 0; off >>= 1) acc += __shfl_down(acc, off, 64);
        if (lane == 0) { dv[c] = acc; di_s[c] = di; }
    }
    __syncthreads();

    __shared__ float wv[TOPK];
    __shared__ int wi[TOPK];
    if (tid == 0) {
        unsigned int used = 0;
        for (int p = 0; p < TOPK; p++) {
            float bv = -FLT_MAX; int bc = -1;
            for (int c = 0; c < NCAND; c++) {
                if (used & (1u << c)) continue;
                const float cv = dv[c];
                if (cv > bv || (cv == bv && di_s[c] < ((bc >= 0) ? di_s[bc] : 0x7fffffff))) { bv = cv; bc = c; }
            }
            used |= 1u << bc;
            wv[p] = dv[bc]; wi[p] = di_s[bc];
        }
    }
    __syncthreads();
    if (tid < TOPK) {
        sel_val[(size_t)token * TOPK + tid] = wv[tid];
        sel_idx[(size_t)token * TOPK + tid] = wi[tid];
        sparse[(size_t)token * DICT_ + wi[tid]] = wv[tid];
    }
}

// ---------------- K5: reconstruction ----------------
__global__ __launch_bounds__(256) void recon_kernel(const float* __restrict__ sel_val,
                                                    const int* __restrict__ sel_idx,
                                                    const float* __restrict__ Wdict,
                                                    float* __restrict__ recon) {
    const int token = blockIdx.x;
    const int tid = threadIdx.x;
    __shared__ float v8[TOPK];
    __shared__ int i8[TOPK];
    if (tid < TOPK) {
        v8[tid] = sel_val[(size_t)token * TOPK + tid];
        i8[tid] = sel_idx[(size_t)token * TOPK + tid];
    }
    __syncthreads();
    float4 acc = {0.f, 0.f, 0.f, 0.f};
    #pragma unroll
    for (int j = 0; j < TOPK; j++) {
        const float4 wv = ((const float4*)(Wdict + (size_t)i8[j] * D_))[tid];
        const float c = v8[j];
        acc.x = fmaf(c, wv.x, acc.x);
        acc.y = fmaf(c, wv.y, acc.y);
        acc.z = fmaf(c, wv.z, acc.z);
        acc.w = fmaf(c, wv.w, acc.w);
    }
    ((float4*)(recon + (size_t)token * D_))[tid] = acc;
}

extern "C" void kernel_launch(void* const* d_in, const int* in_sizes, int n_in,
                              void* d_out, int out_size, void* d_ws, size_t ws_size,
                              hipStream_t stream) {
    const float* x = (const float*)d_in[0];
    const float* gamma = (const float*)d_in[1];
    const float* beta = (const float*)d_in[2];
    const float* Wenc = (const float*)d_in[3];
    const float* Wdict = (const float*)d_in[4];

    float* recon = (float*)d_out;
    float* sparse = (float*)d_out + (size_t)NTOK * D_;

    // scratch carved out of the (later re-zeroed) sparse output region:
    unsigned short* Lg = (unsigned short*)sparse;                 // bf16 logits, 134 MB
    unsigned short* We = Lg + (size_t)NTOK * DICT_;               // bf16 W_enc, 33.5 MB
    unsigned short* Nb = We + (size_t)DICT_ * D_;                 // bf16 normed, 8 MB

    int* cand = (int*)d_ws;                                       // 4096*12 int
    float* sel_val = (float*)(cand + (size_t)NTOK * NCAND);       // 4096*8 f32
    int* sel_idx = (int*)(sel_val + (size_t)NTOK * TOPK);         // 4096*8 int

    ln_kernel<<<NTOK, 256, 0, stream>>>(x, gamma, beta, Nb);
    cvt_kernel<<<DICT_ * D_ / 4096, 256, 0, stream>>>(Wenc, We);

    dim3 gg(DICT_ / 256, NTOK / 256);
    gemm_kernel<<<gg, 512, 0, stream>>>(Nb, We, Lg);

    cand_kernel<<<NTOK, 256, 0, stream>>>(Lg, cand);

    hipMemsetAsync(sparse, 0, (size_t)NTOK * DICT_ * sizeof(float), stream);

    refine_kernel<<<NTOK, 256, 0, stream>>>(x, gamma, beta, Wenc, cand,
                                            sparse, sel_val, sel_idx);

    recon_kernel<<<NTOK, 256, 0, stream>>>(sel_val, sel_idx, Wdict, recon);
}